// Round 4
// baseline (349.300 us; speedup 1.0000x reference)
//
#include <hip/hip_runtime.h>
#include <math.h>
#include <stdint.h>

// ---------------------------------------------------------------------------
// Mlp_8744553415182 on MI355X (gfx950). FP32 I/O; bf16 MFMA compute.
//   1. prep_kernel:  x->xb(+xpad,s_x), W1->w1b(+w1pad,s_w), W2->w2b, s_b, counts=0
//   2. gemm1_topk:   z=0: h = gelu(x.W1^T+b1) (256x256 tile, K=1024)
//                    z=1: counts[n] += #(x_topk.w1_topk+b1 > 0) (K=128)
//   3. fixup_kernel: channels with counts<=2048 -> exact quantized path
//   4. gemm2_bias:   out = h.W2^T + b2 (256x128 tile, K=4096)
// R9->R10: schedule variants (R0 naive / R7 ring / R8 coarse / R9 8-phase) all
// converge at ~104-117us => LDS read service is the shared serial resource
// (ratio 384-512 B/MFMA) and registers cap waves at ~8/CU (R9 occupancy 21.9%
// with 240 regs/wave). Fix the RATIO: per-wave 128x128 tile (256 B/MFMA) so
// LDS service/slice (~750-1100cy) <= matrix/slice (~1040cy). 4 waves/block,
// 1 block/CU, launch_bounds(256,1) to allow ~340 VGPR/wave (no spill <450).
//   gemm1: 256x256 tile, ring-3 x 32k-slice (96 KB), 2 phases/slice
//          {RD_A8+RD_B4+STG8 | bar | 32 MFMA | bar} {RD_B4 | bar | 32 MFMA |
//           WAITV(8) | bar}  (counted vmcnt never 0 mid-loop)
//   gemm2: 256x128 tile (N=1024 needs 256 blocks), ring-3 x 64k-slice
//          (144 KB), 4 phases/slice, WAITV(12).
// XOR swizzle (R3: 0 conflicts) + slab epilogues + topk fusion kept.
// ---------------------------------------------------------------------------

typedef __bf16 v8bf __attribute__((ext_vector_type(8)));
typedef float v4f __attribute__((ext_vector_type(4)));
typedef unsigned short v8us __attribute__((ext_vector_type(8)));

#define AS_G __attribute__((address_space(1)))
#define AS_L __attribute__((address_space(3)))
#define GLOAD(gp, lp) __builtin_amdgcn_global_load_lds((const AS_G void*)(gp), (AS_L void*)(lp), 16, 0, 0)
#define WAITV(n) asm volatile("s_waitcnt vmcnt(" #n ")" ::: "memory")
#define FENCE() __builtin_amdgcn_sched_barrier(0)
#define BAR() __builtin_amdgcn_s_barrier()

__device__ __forceinline__ unsigned short f2bf(float f) {
    union { float f; unsigned int i; } v; v.f = f;
    unsigned int r = v.i + 0x7fffu + ((v.i >> 16) & 1u);   // RNE
    return (unsigned short)(r >> 16);
}
__device__ __forceinline__ float gelu_fast(float v) {
    float u = v * (0.79788456080286536f + 0.035677408136300125f * v * v);
    u = fminf(fmaxf(u, -15.f), 15.f);
    float e = __expf(2.0f * u);
    return v * e * __builtin_amdgcn_rcpf(e + 1.0f);   // v*e/(e+1) = 0.5v(1+tanh u)
}
__device__ __forceinline__ float gelu_exact(float v) {
    return 0.5f * v * (1.0f + erff(v * 0.70710678118654752440f));
}

// --------------------------- core 1: 256x256, per-wave 128x128 --------------
// 4 waves (wm=wave&1 rows, wn=wave>>1 cols). Slice = one 32-k: A blocks
// rb 0..15 at rb*512 shorts, B nb 0..15 at 8192+nb*512; block = 16 rows x 32 k
// bf16, XOR-swizzled (writer: lane l -> global row l>>2, kchunk
// ((l&3)^((l>>3)&3))*8, LDS linear lane*16B; reader roff=R*32+((Q^((R>>1)&3))*8)).
// Ring-3 slices (96 KB). Stage 8 loads/wave/slice (4 A + 4 B).
__device__ __forceinline__ void core_g1(const unsigned short* __restrict__ A,
                                        const unsigned short* __restrict__ B,
                                        const int K, const int bm0, const int bn0,
                                        unsigned short* lds, v4f (&acc)[8][8])
{
    const int tid = threadIdx.x;
    const int wave = tid >> 6, lane = tid & 63;
    const int wm = wave & 1, wn = wave >> 1;
    const int rowInChunk = lane >> 2;
    const int col8 = ((lane & 3) ^ ((lane >> 3) & 3)) * 8;
    const int ldsLane = lane * 8;
    const int R = lane & 15, Q = lane >> 4;
    const int roff = R * 32 + ((Q ^ ((R >> 1) & 3)) * 8);
    const int NS = K >> 5;

    size_t aR[4], bR[4];
#pragma unroll
    for (int r = 0; r < 4; ++r) {
        aR[r] = (size_t)(bm0 + (wave * 4 + r) * 16 + rowInChunk) * K + col8;
        bR[r] = (size_t)(bn0 + (wave * 4 + r) * 16 + rowInChunk) * K + col8;
    }

    v8bf Ar[8], Br[4];

#define G1_STG(c, s) { _Pragma("unroll") \
    for (int r = 0; r < 4; ++r) { \
        GLOAD(A + aR[r] + (c) * 32, (s) + (wave * 4 + r) * 512 + ldsLane); \
        GLOAD(B + bR[r] + (c) * 32, (s) + 8192 + (wave * 4 + r) * 512 + ldsLane); } }
#define G1_RDA(s) { _Pragma("unroll") \
    for (int mf = 0; mf < 8; ++mf) \
        Ar[mf] = *(const v8bf*)&(s)[(wm * 8 + mf) * 512 + roff]; }
#define G1_RDB(s, fg) { _Pragma("unroll") \
    for (int nf = 0; nf < 4; ++nf) \
        Br[nf] = *(const v8bf*)&(s)[8192 + (wn * 8 + (fg) * 4 + nf) * 512 + roff]; }
#define G1_MM(fg) \
    __builtin_amdgcn_s_setprio(1); \
    _Pragma("unroll") for (int mf = 0; mf < 8; ++mf) { \
    _Pragma("unroll") for (int nf = 0; nf < 4; ++nf) \
        acc[mf][(fg) * 4 + nf] = __builtin_amdgcn_mfma_f32_16x16x32_bf16(Ar[mf], Br[nf], acc[mf][(fg) * 4 + nf], 0, 0, 0); } \
    __builtin_amdgcn_s_setprio(0);

    unsigned short* pc = lds;
    unsigned short* pn = lds + 16384;
    unsigned short* ps = lds + 32768;

    G1_STG(0, pc); G1_STG(1, pn);
    WAITV(8);                      // slice 0 landed; slice 1 (8 loads) in flight
    FENCE(); BAR(); FENCE();

    for (int c = 0; c < NS - 2; ++c) {
        G1_RDA(pc); G1_RDB(pc, 0); G1_STG(c + 2, ps);
        FENCE(); BAR(); FENCE();
        G1_MM(0);
        FENCE(); BAR(); FENCE();
        G1_RDB(pc, 1);
        FENCE(); BAR(); FENCE();
        G1_MM(1); WAITV(8);        // slice c+1 landed; c+2 stays in flight
        FENCE(); BAR(); FENCE();
        unsigned short* t = pc; pc = pn; pn = ps; ps = t;
    }
    // slice NS-2
    G1_RDA(pc); G1_RDB(pc, 0);
    FENCE(); BAR(); FENCE();
    G1_MM(0);
    FENCE(); BAR(); FENCE();
    G1_RDB(pc, 1);
    FENCE(); BAR(); FENCE();
    G1_MM(1); WAITV(0);            // last slice landed
    FENCE(); BAR(); FENCE();
    { unsigned short* t = pc; pc = pn; pn = ps; ps = t; }
    // slice NS-1
    G1_RDA(pc); G1_RDB(pc, 0);
    FENCE(); BAR(); FENCE();
    G1_MM(0);
    FENCE(); BAR(); FENCE();
    G1_RDB(pc, 1);
    FENCE(); BAR(); FENCE();
    G1_MM(1);
    FENCE(); BAR(); FENCE();
#undef G1_STG
#undef G1_RDA
#undef G1_RDB
#undef G1_MM
}

// --------------------------- core 2: 256x128, per-wave 128x64 ---------------
// 4 waves (wm rows of 128, wn cols of 64). Slice = one 64-k: A blocks
// (rb*2+ks)*512, rb 0..15; B at 16384+(nb*2+ks)*512, nb 0..7. 48 KB/slice,
// ring-3 = 144 KB. Stage 12 loads/wave/slice (8 A + 4 B). 4 phases/slice.
__device__ __forceinline__ void core_g2(const unsigned short* __restrict__ A,
                                        const unsigned short* __restrict__ B,
                                        const int K, const int bm0, const int bn0,
                                        unsigned short* lds, v4f (&acc)[8][4])
{
    const int tid = threadIdx.x;
    const int wave = tid >> 6, lane = tid & 63;
    const int wm = wave & 1, wn = wave >> 1;
    const int rowInChunk = lane >> 2;
    const int col8 = ((lane & 3) ^ ((lane >> 3) & 3)) * 8;
    const int ldsLane = lane * 8;
    const int R = lane & 15, Q = lane >> 4;
    const int roff = R * 32 + ((Q ^ ((R >> 1) & 3)) * 8);
    const int NS = K >> 6;

    size_t aR[4], bR[2];
#pragma unroll
    for (int r = 0; r < 4; ++r)
        aR[r] = (size_t)(bm0 + (wave * 4 + r) * 16 + rowInChunk) * K + col8;
#pragma unroll
    for (int r = 0; r < 2; ++r)
        bR[r] = (size_t)(bn0 + (wave * 2 + r) * 16 + rowInChunk) * K + col8;

    v8bf Ar[8], Br[2];

#define G2_STG(c, s) { _Pragma("unroll") \
    for (int r = 0; r < 4; ++r) { _Pragma("unroll") \
        for (int ks = 0; ks < 2; ++ks) \
            GLOAD(A + aR[r] + (c) * 64 + ks * 32, (s) + ((wave * 4 + r) * 2 + ks) * 512 + ldsLane); } \
    _Pragma("unroll") \
    for (int r = 0; r < 2; ++r) { _Pragma("unroll") \
        for (int ks = 0; ks < 2; ++ks) \
            GLOAD(B + bR[r] + (c) * 64 + ks * 32, (s) + 16384 + ((wave * 2 + r) * 2 + ks) * 512 + ldsLane); } }
#define G2_RDA(s, ks) { _Pragma("unroll") \
    for (int mf = 0; mf < 8; ++mf) \
        Ar[mf] = *(const v8bf*)&(s)[((wm * 8 + mf) * 2 + (ks)) * 512 + roff]; }
#define G2_RDB(s, ks, fg) { _Pragma("unroll") \
    for (int nf = 0; nf < 2; ++nf) \
        Br[nf] = *(const v8bf*)&(s)[16384 + ((wn * 4 + (fg) * 2 + nf) * 2 + (ks)) * 512 + roff]; }
#define G2_MM(fg) \
    __builtin_amdgcn_s_setprio(1); \
    _Pragma("unroll") for (int mf = 0; mf < 8; ++mf) { \
    _Pragma("unroll") for (int nf = 0; nf < 2; ++nf) \
        acc[mf][(fg) * 2 + nf] = __builtin_amdgcn_mfma_f32_16x16x32_bf16(Ar[mf], Br[nf], acc[mf][(fg) * 2 + nf], 0, 0, 0); } \
    __builtin_amdgcn_s_setprio(0);
#define G2_PH(s, ks, fg) \
    FENCE(); BAR(); FENCE(); \
    G2_MM(fg); \
    FENCE(); BAR(); FENCE();

    unsigned short* pc = lds;
    unsigned short* pn = lds + 24576;
    unsigned short* ps = lds + 49152;

    G2_STG(0, pc); G2_STG(1, pn);
    WAITV(12);                     // slice 0 landed; slice 1 (12) in flight
    FENCE(); BAR(); FENCE();

    for (int c = 0; c < NS - 2; ++c) {
        G2_RDA(pc, 0); G2_RDB(pc, 0, 0); G2_STG(c + 2, ps);
        FENCE(); BAR(); FENCE();
        G2_MM(0);
        FENCE(); BAR(); FENCE();
        G2_RDB(pc, 0, 1);
        FENCE(); BAR(); FENCE();
        G2_MM(1);
        FENCE(); BAR(); FENCE();
        G2_RDA(pc, 1); G2_RDB(pc, 1, 0);
        FENCE(); BAR(); FENCE();
        G2_MM(0);
        FENCE(); BAR(); FENCE();
        G2_RDB(pc, 1, 1);
        FENCE(); BAR(); FENCE();
        G2_MM(1); WAITV(12);       // slice c+1 landed; c+2 stays in flight
        FENCE(); BAR(); FENCE();
        unsigned short* t = pc; pc = pn; pn = ps; ps = t;
    }
    for (int c = 0; c < 2; ++c) {  // slices NS-2 (wait 0) and NS-1
        G2_RDA(pc, 0); G2_RDB(pc, 0, 0);
        FENCE(); BAR(); FENCE();
        G2_MM(0);
        FENCE(); BAR(); FENCE();
        G2_RDB(pc, 0, 1);
        FENCE(); BAR(); FENCE();
        G2_MM(1);
        FENCE(); BAR(); FENCE();
        G2_RDA(pc, 1); G2_RDB(pc, 1, 0);
        FENCE(); BAR(); FENCE();
        G2_MM(0);
        FENCE(); BAR(); FENCE();
        G2_RDB(pc, 1, 1);
        FENCE(); BAR(); FENCE();
        G2_MM(1);
        if (c == 0) { WAITV(0); }
        FENCE(); BAR(); FENCE();
        unsigned short* t = pc; pc = pn; pn = ps; ps = t;
    }
#undef G2_STG
#undef G2_RDA
#undef G2_RDB
#undef G2_MM
#undef G2_PH
}

// --------------------------- prep (fused) -----------------------------------
__global__ void prep_kernel(const float* __restrict__ x, const float* __restrict__ W1,
                            const float* __restrict__ W2, const float* __restrict__ b1,
                            unsigned short* __restrict__ xb, unsigned short* __restrict__ w1b,
                            unsigned short* __restrict__ w2b,
                            unsigned short* __restrict__ xpad, unsigned short* __restrict__ w1pad,
                            float* __restrict__ s_x, float* __restrict__ s_w,
                            float* __restrict__ s_b, int* __restrict__ counts)
{
    const int b = blockIdx.x, t = threadIdx.x;
    __shared__ float red[4];

    if (b < 16384) {
        const float* src; unsigned short* dst; unsigned short* pad = nullptr; float* sc = nullptr;
        if (b < 8192)       { src = x  + (size_t)b * 1024;            dst = xb  + (size_t)b * 1024;
                              pad = xpad  + (size_t)b * 128;          sc = s_x + b; }
        else if (b < 12288) { int r = b - 8192;  src = W1 + (size_t)r * 1024; dst = w1b + (size_t)r * 1024;
                              pad = w1pad + (size_t)r * 128;          sc = s_w + r; }
        else                { int r = b - 12288; src = W2 + (size_t)r * 1024; dst = w2b + (size_t)r * 1024; }

        float4 v = ((const float4*)src)[t];
        ushort4 u;
        u.x = f2bf(v.x); u.y = f2bf(v.y); u.z = f2bf(v.z); u.w = f2bf(v.w);
        ((ushort4*)dst)[t] = u;
        if (pad && t < 32) {
            int c = t * 4;
            ushort4 p;
            p.x = (c + 0 < 103) ? u.x : (unsigned short)0;
            p.y = (c + 1 < 103) ? u.y : (unsigned short)0;
            p.z = (c + 2 < 103) ? u.z : (unsigned short)0;
            p.w = (c + 3 < 103) ? u.w : (unsigned short)0;
            ((ushort4*)pad)[t] = p;
        }
        if (sc) {
            float m = fmaxf(fmaxf(fabsf(v.x), fabsf(v.y)), fmaxf(fabsf(v.z), fabsf(v.w)));
#pragma unroll
            for (int off = 32; off; off >>= 1) m = fmaxf(m, __shfl_xor(m, off, 64));
            if ((t & 63) == 0) red[t >> 6] = m;
            __syncthreads();
            if (t == 0) {
                m = fmaxf(fmaxf(red[0], red[1]), fmaxf(red[2], red[3]));
                *sc = fmaxf(m, 1e-5f) * (1.0f / 127.0f);
            }
        }
    } else {
        float m = 0.f;
        for (int k = t; k < 4096; k += 256) { m = fmaxf(m, fabsf(b1[k])); counts[k] = 0; }
#pragma unroll
        for (int off = 32; off; off >>= 1) m = fmaxf(m, __shfl_xor(m, off, 64));
        if ((t & 63) == 0) red[t >> 6] = m;
        __syncthreads();
        if (t == 0) {
            m = fmaxf(fmaxf(red[0], red[1]), fmaxf(red[2], red[3]));
            *s_b = fmaxf(m, 1e-5f) * (1.0f / 127.0f);
        }
    }
}

// --------------------------- gemm1 + topk (fused dispatch) -------------------
// grid (16, 32, 2): x = N-block, y = M-block, z = path. 256 threads (4 waves),
// 96 KB LDS, 1 block/CU, ~340 VGPR/wave allowed by launch_bounds(256,1).
__global__ __launch_bounds__(256, 1)
void gemm1_topk(const unsigned short* __restrict__ xb,
                const unsigned short* __restrict__ w1b,
                const unsigned short* __restrict__ xpad,
                const unsigned short* __restrict__ w1pad,
                const float* __restrict__ b1,
                unsigned short* __restrict__ hbuf,
                int* __restrict__ counts)
{
    __shared__ unsigned short lds[49152];   // 96 KB: ring-3 x 32 KB slices
    v4f acc[8][8];
    v4f z = {0.f, 0.f, 0.f, 0.f};
#pragma unroll
    for (int i = 0; i < 8; ++i)
#pragma unroll
        for (int j = 0; j < 8; ++j) acc[i][j] = z;

    const int bn0 = blockIdx.x * 256, bm0 = blockIdx.y * 256;
    const int tid = threadIdx.x;
    const int lane = tid & 63, wave = tid >> 6;
    const int wm = wave & 1, wn = wave >> 1, q = lane >> 4;
    const int R = lane & 15;

    if (blockIdx.z == 0) {
        core_g1(xb, w1b, 1024, bm0, bn0, lds, acc);

        float bvj[8];
#pragma unroll
        for (int nf = 0; nf < 8; ++nf) bvj[nf] = b1[bn0 + wn * 128 + nf * 16 + R];

        unsigned short* slab = lds;          // 64 x 256 bf16 = 32 KB
#pragma unroll
        for (int p = 0; p < 4; ++p) {
            __syncthreads();
            if (wm == (p >> 1)) {
                const int mfb = (p & 1) * 4;
#pragma unroll
                for (int mfp = 0; mfp < 4; ++mfp)
#pragma unroll
                    for (int nf = 0; nf < 8; ++nf) {
                        const int colq = wn * 128 + nf * 16 + R;
#pragma unroll
                        for (int r = 0; r < 4; ++r)
                            slab[(mfp * 16 + q * 4 + r) * 256 + colq] =
                                f2bf(gelu_fast(acc[mfb + mfp][nf][r] + bvj[nf]));
                    }
            }
            __syncthreads();
#pragma unroll
            for (int s = 0; s < 8; ++s) {
                const int idx = s * 256 + tid;          // 0..2047
                const int row = idx >> 5, ch = idx & 31;
                *(v8us*)&hbuf[(size_t)(bm0 + p * 64 + row) * 4096 + bn0 + ch * 8] =
                    *(const v8us*)&slab[row * 256 + ch * 8];
            }
        }
    } else {
        core_g1(xpad, w1pad, 128, bm0, bn0, lds, acc);

#pragma unroll
        for (int nf = 0; nf < 8; ++nf) {
            const int n = bn0 + wn * 128 + nf * 16 + R;
            const float bv = b1[n];
            int cnt = 0;
#pragma unroll
            for (int mf = 0; mf < 8; ++mf)
#pragma unroll
                for (int r = 0; r < 4; ++r)
                    cnt += (acc[mf][nf][r] + bv > 0.0f) ? 1 : 0;
            cnt += __shfl_xor(cnt, 16, 64);
            cnt += __shfl_xor(cnt, 32, 64);
            if (lane < 16 && cnt) atomicAdd(&counts[n], cnt);
        }
    }
}

// --------------------------- fixup (exact quant path) ------------------------
__global__ void fixup_kernel(const float* __restrict__ x,
                             const float* __restrict__ W1,
                             const float* __restrict__ b1,
                             const int* __restrict__ counts,
                             const float* __restrict__ s_x,
                             const float* __restrict__ s_w,
                             const float* __restrict__ s_b,
                             unsigned short* __restrict__ hbuf)
{
    const int n = blockIdx.x;
    if (counts[n] > 2048) return;   // fp channel: keep gemm1 result
    __shared__ float qw[1024];
    const float swn = s_w[n];
    for (int k = threadIdx.x; k < 1024; k += 256) {
        float q = nearbyintf(W1[(size_t)n * 1024 + k] / swn);
        qw[k] = fminf(fmaxf(q, -128.f), 127.f) * swn;
    }
    __syncthreads();
    const float sb = *s_b;
    const float bq = fminf(fmaxf(nearbyintf(b1[n] / sb), -128.f), 127.f) * sb;
    for (int m = threadIdx.x; m < 8192; m += 256) {
        const float sxm = s_x[m];
        float a = 0.f;
        for (int k = 0; k < 1024; ++k) {
            float q = nearbyintf(x[(size_t)m * 1024 + k] / sxm);
            a += fminf(fmaxf(q, -128.f), 127.f) * sxm * qw[k];
        }
        hbuf[(size_t)m * 4096 + n] = f2bf(gelu_exact(a + bq));
    }
}

// --------------------------- gemm2 + bias (256x128 tile) ---------------------
// grid (8, 32) = 256 blocks, 1/CU (all co-resident). 144 KB LDS ring.
// Epilogue: 4 passes of 64x128 fp32 slab (32 KB), coalesced float4 out.
__global__ __launch_bounds__(256, 1)
void gemm2_bias(const unsigned short* __restrict__ hbuf,
                const unsigned short* __restrict__ w2b,
                const float* __restrict__ b2,
                float* __restrict__ out)
{
    __shared__ unsigned short lds[73728];   // 144 KB: ring-3 x 48 KB slices
    v4f acc[8][4];
    v4f z = {0.f, 0.f, 0.f, 0.f};
#pragma unroll
    for (int i = 0; i < 8; ++i)
#pragma unroll
        for (int j = 0; j < 4; ++j) acc[i][j] = z;

    const int bn0 = blockIdx.x * 128, bm0 = blockIdx.y * 256;
    const int tid = threadIdx.x;
    const int lane = tid & 63, wave = tid >> 6;
    const int wm = wave & 1, wn = wave >> 1, q = lane >> 4;
    const int R = lane & 15;

    core_g2(hbuf, w2b, 4096, bm0, bn0, lds, acc);

    float bvj[4];
#pragma unroll
    for (int nf = 0; nf < 4; ++nf) bvj[nf] = b2[bn0 + wn * 64 + nf * 16 + R];

    float* slabf = (float*)lds;             // 64 x 128 fp32 = 32 KB
#pragma unroll
    for (int p = 0; p < 4; ++p) {
        __syncthreads();
        if (wm == (p >> 1)) {
            const int mfb = (p & 1) * 4;
#pragma unroll
            for (int mfp = 0; mfp < 4; ++mfp)
#pragma unroll
                for (int nf = 0; nf < 4; ++nf) {
                    const int colq = wn * 64 + nf * 16 + R;
#pragma unroll
                    for (int r = 0; r < 4; ++r)
                        slabf[(mfp * 16 + q * 4 + r) * 128 + colq] =
                            acc[mfb + mfp][nf][r] + bvj[nf];
                }
        }
        __syncthreads();
#pragma unroll
        for (int s = 0; s < 8; ++s) {
            const int idx = s * 256 + tid;           // 0..2047
            const int row = idx >> 5, ch = idx & 31; // 64 rows x 32 float4
            *(float4*)&out[(size_t)(bm0 + p * 64 + row) * 1024 + bn0 + ch * 4] =
                *(const float4*)&slabf[row * 128 + ch * 4];
        }
    }
}

// --------------------------- launch ----------------------------------------
extern "C" void kernel_launch(void* const* d_in, const int* in_sizes, int n_in,
                              void* d_out, int out_size, void* d_ws, size_t ws_size,
                              hipStream_t stream)
{
    const float* x  = (const float*)d_in[0];   // [4,2048,1024] fp32
    const float* W1 = (const float*)d_in[1];   // [4096,1024]
    const float* b1 = (const float*)d_in[2];   // [4096]
    const float* W2 = (const float*)d_in[3];   // [1024,4096]
    const float* b2 = (const float*)d_in[4];   // [1024]
    float* out = (float*)d_out;                // [4,2048,1024] fp32 (32 MB)

    // bf16 copies of x and W1 parked in d_out (dead until gemm2 writes it):
    unsigned short* xb  = (unsigned short*)d_out;                       // 16 MB
    unsigned short* w1b = (unsigned short*)d_out + (size_t)8192 * 1024; // 8 MB

    char* ws = (char*)d_ws;
    int*   counts = (int*)(ws + 0);                       // 16 KB
    float* s_x    = (float*)(ws + (64 << 10));            // 32 KB
    float* s_w    = (float*)(ws + (96 << 10));            // 16 KB
    float* s_b    = (float*)(ws + (112 << 10));           // 4 B
    unsigned short* xpad  = (unsigned short*)(ws + (1 << 20));   // 2 MB
    unsigned short* w1pad = (unsigned short*)(ws + (3 << 20));   // 1 MB
    unsigned short* w2b   = (unsigned short*)(ws + (4 << 20));   // 8 MB
    unsigned short* hbuf  = (unsigned short*)(ws + (12 << 20));  // 64 MB -> 76 MB total

    prep_kernel<<<16385, 256, 0, stream>>>(x, W1, W2, b1, xb, w1b, w2b,
                                           xpad, w1pad, s_x, s_w, s_b, counts);
    gemm1_topk<<<dim3(16, 32, 2), 256, 0, stream>>>(xb, w1b, xpad, w1pad, b1, hbuf, counts);
    fixup_kernel<<<4096, 256, 0, stream>>>(x, W1, b1, counts, s_x, s_w, s_b, hbuf);
    gemm2_bias<<<dim3(8, 32), 256, 0, stream>>>(hbuf, w2b, b2, out);
}